// Round 1
// 949.981 us; speedup vs baseline: 1.0917x; 1.0917x over previous
//
#include <hip/hip_runtime.h>
#include <hip/hip_bf16.h>

#define VOCAB 32000
#define EMB   64
#define HID   64
#define NB    16
#define NS    256
#define G3    192   // 3*HID

typedef __bf16 bf16x8  __attribute__((ext_vector_type(8)));
typedef short  short8  __attribute__((ext_vector_type(8)));
typedef short  short4v __attribute__((ext_vector_type(4)));
typedef float  floatx4 __attribute__((ext_vector_type(4)));

__device__ __forceinline__ float bf2f(__hip_bfloat16 v) { return __bfloat162float(v); }

// RNE fp32 -> bf16 bit pattern (no NaN inputs possible here)
__device__ __forceinline__ short f2bf_bits(float f) {
    unsigned int u = __float_as_uint(f);
    unsigned int r = (u + 0x7FFFu + ((u >> 16) & 1u)) >> 16;
    return (short)r;
}

// Runtime dtype detection: true if the array at p holds bf16 data, false if fp32.
__device__ __forceinline__ bool detect_bf16(const void* p) {
    const unsigned int* w = (const unsigned int*)p;
    unsigned int word = w[threadIdx.x & 63];
    unsigned int e = (word >> 7) & 0xFFu;
    int pred = (e >= 115u) && (e <= 130u);
    unsigned long long m = __ballot(pred);
    return __popcll(m) > 32;
}

// lane-broadcast of a float via v_readlane
__device__ __forceinline__ float bcastf(float v, int l) {
    return __uint_as_float(__builtin_amdgcn_readlane(__float_as_uint(v), l));
}

// ---------------------------------------------------------------------------
// K1: xp[m][g] = sum_e emb[tok[m]][e] * w_ih[g][e] + b_ih[g]   (m = b*NS + s)
// ---------------------------------------------------------------------------
__global__ __launch_bounds__(G3) void k_embed_proj(
    const int* __restrict__ tokens,
    const void* __restrict__ emb_raw,
    const void* __restrict__ w_ih_raw,
    const void* __restrict__ b_ih_raw,
    float* __restrict__ xp)
{
    const bool isbf = detect_bf16(w_ih_raw);
    __shared__ float e_s[EMB];
    const int m   = blockIdx.x;
    const int tid = threadIdx.x;
    const int tok = tokens[m];
    if (tid < EMB) {
        e_s[tid] = isbf ? bf2f(((const __hip_bfloat16*)emb_raw)[tok * EMB + tid])
                        : ((const float*)emb_raw)[tok * EMB + tid];
    }
    __syncthreads();

    float acc = isbf ? bf2f(((const __hip_bfloat16*)b_ih_raw)[tid])
                     : ((const float*)b_ih_raw)[tid];
    if (isbf) {
        const __hip_bfloat16* wrow = (const __hip_bfloat16*)w_ih_raw + tid * EMB;
#pragma unroll
        for (int k0 = 0; k0 < EMB; k0 += 8) {
            bf16x8 wv = *reinterpret_cast<const bf16x8*>(wrow + k0);
#pragma unroll
            for (int j = 0; j < 8; ++j) acc += e_s[k0 + j] * (float)wv[j];
        }
    } else {
        const float* wrow = (const float*)w_ih_raw + tid * EMB;
#pragma unroll
        for (int k0 = 0; k0 < EMB; k0 += 4) {
            floatx4 wv = *reinterpret_cast<const floatx4*>(wrow + k0);
#pragma unroll
            for (int j = 0; j < 4; ++j) acc += e_s[k0 + j] * wv[j];
        }
    }
    xp[m * G3 + tid] = acc;
}

// ---------------------------------------------------------------------------
// K2: sequential GRU scan — ONE WAVE PER BATCH, zero barriers, zero LDS.
// Thread j owns hidden unit j and holds all three w_hh rows (r/z/n) in
// 192 fp32 VGPRs. h lives in lane j; broadcast via v_readlane. Next-step
// xp is prefetched into registers so HBM latency hides under the dot.
// Fast transcendentals (v_exp_f32 / v_rcp_f32) replace libm expf/tanhf.
// ---------------------------------------------------------------------------
__global__ __launch_bounds__(64, 1) void k_gru_scan(
    const float* __restrict__ xp,
    const void* __restrict__ w_hh_raw,
    const void* __restrict__ b_hh_raw,
    __hip_bfloat16* __restrict__ hs)
{
    const bool isbf = detect_bf16(w_hh_raw);
    const int b = blockIdx.x;
    const int j = threadIdx.x;   // 0..63, owns hidden unit j

    float wr[HID], wz[HID], wn[HID];
    if (isbf) {
        const __hip_bfloat16* w = (const __hip_bfloat16*)w_hh_raw;
#pragma unroll
        for (int k0 = 0; k0 < HID; k0 += 8) {
            bf16x8 v0 = *reinterpret_cast<const bf16x8*>(w + (          j) * HID + k0);
            bf16x8 v1 = *reinterpret_cast<const bf16x8*>(w + (HID     + j) * HID + k0);
            bf16x8 v2 = *reinterpret_cast<const bf16x8*>(w + (2 * HID + j) * HID + k0);
#pragma unroll
            for (int t = 0; t < 8; ++t) {
                wr[k0 + t] = (float)v0[t];
                wz[k0 + t] = (float)v1[t];
                wn[k0 + t] = (float)v2[t];
            }
        }
    } else {
        const float* w = (const float*)w_hh_raw;
#pragma unroll
        for (int k0 = 0; k0 < HID; k0 += 4) {
            floatx4 v0 = *reinterpret_cast<const floatx4*>(w + (          j) * HID + k0);
            floatx4 v1 = *reinterpret_cast<const floatx4*>(w + (HID     + j) * HID + k0);
            floatx4 v2 = *reinterpret_cast<const floatx4*>(w + (2 * HID + j) * HID + k0);
#pragma unroll
            for (int t = 0; t < 4; ++t) {
                wr[k0 + t] = v0[t];
                wz[k0 + t] = v1[t];
                wn[k0 + t] = v2[t];
            }
        }
    }

    float bhr, bhz, bhn;
    if (isbf) {
        const __hip_bfloat16* bb = (const __hip_bfloat16*)b_hh_raw;
        bhr = bf2f(bb[j]); bhz = bf2f(bb[HID + j]); bhn = bf2f(bb[2 * HID + j]);
    } else {
        const float* bb = (const float*)b_hh_raw;
        bhr = bb[j]; bhz = bb[HID + j]; bhn = bb[2 * HID + j];
    }

    const float* xpb = xp + (size_t)b * NS * G3;
    float xr = xpb[j], xz = xpb[HID + j], xn = xpb[2 * HID + j];
    float h = 0.f;

    for (int s = 0; s < NS; ++s) {
        // prefetch next step's x-projections (independent of h; hides HBM latency)
        float nxr = 0.f, nxz = 0.f, nxn = 0.f;
        if (s + 1 < NS) {
            const float* xrow = xpb + (s + 1) * G3;
            nxr = xrow[j]; nxz = xrow[HID + j]; nxn = xrow[2 * HID + j];
        }

        float ar0 = 0.f, ar1 = 0.f, az0 = 0.f, az1 = 0.f, an0 = 0.f, an1 = 0.f;
#pragma unroll
        for (int k = 0; k < HID; k += 2) {
            const float h0 = bcastf(h, k);
            const float h1 = bcastf(h, k + 1);
            ar0 += h0 * wr[k];     ar1 += h1 * wr[k + 1];
            az0 += h0 * wz[k];     az1 += h1 * wz[k + 1];
            an0 += h0 * wn[k];     an1 += h1 * wn[k + 1];
        }

        const float r = __fdividef(1.f, 1.f + __expf(-(xr + ar0 + ar1 + bhr)));
        const float z = __fdividef(1.f, 1.f + __expf(-(xz + az0 + az1 + bhz)));
        const float n = __fdividef(2.f, 1.f + __expf(-2.f * (xn + r * (an0 + an1 + bhn)))) - 1.f;
        h = (1.f - z) * n + z * h;

        hs[((size_t)b * NS + s) * HID + j] = __float2bfloat16(h);
        xr = nxr; xz = nxz; xn = nxn;
    }
}

// ---------------------------------------------------------------------------
// K3: out[m][v] = sum_k hs[m][k] * w_out[v][k] + b_out[v].
// mfma_f32_16x16x32_bf16; block = 4 waves, each wave does 16(M)x64(N).
// NEW: stage the 16x64 wave tile through LDS, then store full 128B-line-
// covered rows (quad writes 16 lanes x float4 = 256 B contiguous) so the
// TCC never fetch-on-partial-writes output lines.
// ---------------------------------------------------------------------------
__global__ __launch_bounds__(256) void k_logits(
    const __hip_bfloat16* __restrict__ hs,
    const void* __restrict__ w_out_raw,
    const void* __restrict__ b_out_raw,
    void* __restrict__ out_raw)
{
    const bool isbf = detect_bf16(w_out_raw);
    const int mtile = blockIdx.y;            // 0..255 (16 rows each)
    const int ncb   = blockIdx.x;            // 0..124 (256 cols each)
    const int wave  = threadIdx.x >> 6;      // 0..3
    const int lane  = threadIdx.x & 63;
    const int quad  = lane >> 4;
    const int l15   = lane & 15;

    // stride 68: keeps 16B alignment for float4 reads, staggers banks by 4/row
    __shared__ float tile[4][16][68];

    const __hip_bfloat16* arow = hs + (mtile * 16 + l15) * HID;
    const bf16x8 a0 = *reinterpret_cast<const bf16x8*>(arow + quad * 8);
    const bf16x8 a1 = *reinterpret_cast<const bf16x8*>(arow + 32 + quad * 8);

    const int ncol_wave = ncb * 256 + wave * 64;
#pragma unroll
    for (int t = 0; t < 4; ++t) {
        const int ncol = ncol_wave + t * 16;
        bf16x8 b0, b1;
        if (isbf) {
            const __hip_bfloat16* brow = (const __hip_bfloat16*)w_out_raw + (ncol + l15) * HID;
            b0 = *reinterpret_cast<const bf16x8*>(brow + quad * 8);
            b1 = *reinterpret_cast<const bf16x8*>(brow + 32 + quad * 8);
        } else {
            const float* browf = (const float*)w_out_raw + (ncol + l15) * HID;
            floatx4 f0 = *reinterpret_cast<const floatx4*>(browf + quad * 8);
            floatx4 f1 = *reinterpret_cast<const floatx4*>(browf + quad * 8 + 4);
            floatx4 f2 = *reinterpret_cast<const floatx4*>(browf + 32 + quad * 8);
            floatx4 f3 = *reinterpret_cast<const floatx4*>(browf + 32 + quad * 8 + 4);
            short8 s0, s1;
#pragma unroll
            for (int j = 0; j < 4; ++j) {
                s0[j] = f2bf_bits(f0[j]); s0[4 + j] = f2bf_bits(f1[j]);
                s1[j] = f2bf_bits(f2[j]); s1[4 + j] = f2bf_bits(f3[j]);
            }
            b0 = __builtin_bit_cast(bf16x8, s0);
            b1 = __builtin_bit_cast(bf16x8, s1);
        }

        floatx4 acc = {0.f, 0.f, 0.f, 0.f};
        acc = __builtin_amdgcn_mfma_f32_16x16x32_bf16(a0, b0, acc, 0, 0, 0);
        acc = __builtin_amdgcn_mfma_f32_16x16x32_bf16(a1, b1, acc, 0, 0, 0);

        const float bias = isbf ? bf2f(((const __hip_bfloat16*)b_out_raw)[ncol + l15])
                                : ((const float*)b_out_raw)[ncol + l15];
        // C layout: col = lane&15, row = quad*4 + i  →  stage into LDS
#pragma unroll
        for (int i = 0; i < 4; ++i)
            tile[wave][quad * 4 + i][t * 16 + l15] = acc[i] + bias;
    }
    __syncthreads();   // LDS visibility (intra-wave dep; barrier is one-shot & cheap)

    // Coalesced writeback: per p, quad q writes row p*4+q, lanes cover 64
    // consecutive floats as float4 → 256 B contiguous, full cache lines.
    if (isbf) {
        short* outb = (short*)out_raw;
#pragma unroll
        for (int p = 0; p < 4; ++p) {
            const int row = p * 4 + quad;
            const float* src = &tile[wave][row][l15 * 4];
            short4v u;
#pragma unroll
            for (int jj = 0; jj < 4; ++jj) u[jj] = f2bf_bits(src[jj]);
            *reinterpret_cast<short4v*>(
                outb + (size_t)(mtile * 16 + row) * VOCAB + ncol_wave + l15 * 4) = u;
        }
    } else {
        float* outf = (float*)out_raw;
#pragma unroll
        for (int p = 0; p < 4; ++p) {
            const int row = p * 4 + quad;
            floatx4 v = *reinterpret_cast<const floatx4*>(&tile[wave][row][l15 * 4]);
            *reinterpret_cast<floatx4*>(
                outf + (size_t)(mtile * 16 + row) * VOCAB + ncol_wave + l15 * 4) = v;
        }
    }
}

// ---------------------------------------------------------------------------
extern "C" void kernel_launch(void* const* d_in, const int* in_sizes, int n_in,
                              void* d_out, int out_size, void* d_ws, size_t ws_size,
                              hipStream_t stream)
{
    const int*  tokens = (const int*)d_in[0];
    const void* emb    = d_in[1];
    const void* w_ih   = d_in[2];
    const void* w_hh   = d_in[3];
    const void* b_ih   = d_in[4];
    const void* b_hh   = d_in[5];
    const void* w_out  = d_in[6];
    const void* b_out  = d_in[7];

    // xp scratch lives in d_out's first 3 MiB (dead until k_logits overwrites
    // the whole output); hs (512 KiB) is the only d_ws use.
    float* xp = (float*)d_out;
    __hip_bfloat16* hs = (__hip_bfloat16*)d_ws;

    k_embed_proj<<<NB * NS, G3, 0, stream>>>(tokens, emb, w_ih, b_ih, xp);
    k_gru_scan<<<NB, 64, 0, stream>>>(xp, w_hh, b_hh, hs);
    dim3 grid3(VOCAB / 256, (NB * NS) / 16);
    k_logits<<<grid3, 256, 0, stream>>>(hs, w_out, b_out, d_out);
}

// Round 2
// 880.156 us; speedup vs baseline: 1.1783x; 1.0793x over previous
//
#include <hip/hip_runtime.h>
#include <hip/hip_bf16.h>

#define VOCAB 32000
#define EMB   64
#define HID   64
#define NB    16
#define NS    256
#define G3    192   // 3*HID

typedef __bf16 bf16x8  __attribute__((ext_vector_type(8)));
typedef short  short8  __attribute__((ext_vector_type(8)));
typedef short  short4v __attribute__((ext_vector_type(4)));
typedef float  floatx4 __attribute__((ext_vector_type(4)));
typedef float  floatx2 __attribute__((ext_vector_type(2)));

__device__ __forceinline__ float bf2f(__hip_bfloat16 v) { return __bfloat162float(v); }

// RNE fp32 -> bf16 bit pattern (no NaN inputs possible here)
__device__ __forceinline__ short f2bf_bits(float f) {
    unsigned int u = __float_as_uint(f);
    unsigned int r = (u + 0x7FFFu + ((u >> 16) & 1u)) >> 16;
    return (short)r;
}

// Runtime dtype detection: true if the array at p holds bf16 data, false if fp32.
__device__ __forceinline__ bool detect_bf16(const void* p) {
    const unsigned int* w = (const unsigned int*)p;
    unsigned int word = w[threadIdx.x & 63];
    unsigned int e = (word >> 7) & 0xFFu;
    int pred = (e >= 115u) && (e <= 130u);
    unsigned long long m = __ballot(pred);
    return __popcll(m) > 32;
}

// lane-broadcast of a float via v_readlane (result is wave-uniform -> SGPR)
__device__ __forceinline__ float bcastf(float v, int l) {
    return __uint_as_float(__builtin_amdgcn_readlane(__float_as_uint(v), l));
}

// ---------------------------------------------------------------------------
// K1: xp[m][g] = sum_e emb[tok[m]][e] * w_ih[g][e] + b_ih[g]   (m = b*NS + s)
// ---------------------------------------------------------------------------
__global__ __launch_bounds__(G3) void k_embed_proj(
    const int* __restrict__ tokens,
    const void* __restrict__ emb_raw,
    const void* __restrict__ w_ih_raw,
    const void* __restrict__ b_ih_raw,
    float* __restrict__ xp)
{
    const bool isbf = detect_bf16(w_ih_raw);
    __shared__ float e_s[EMB];
    const int m   = blockIdx.x;
    const int tid = threadIdx.x;
    const int tok = tokens[m];
    if (tid < EMB) {
        e_s[tid] = isbf ? bf2f(((const __hip_bfloat16*)emb_raw)[tok * EMB + tid])
                        : ((const float*)emb_raw)[tok * EMB + tid];
    }
    __syncthreads();

    float acc = isbf ? bf2f(((const __hip_bfloat16*)b_ih_raw)[tid])
                     : ((const float*)b_ih_raw)[tid];
    if (isbf) {
        const __hip_bfloat16* wrow = (const __hip_bfloat16*)w_ih_raw + tid * EMB;
#pragma unroll
        for (int k0 = 0; k0 < EMB; k0 += 8) {
            bf16x8 wv = *reinterpret_cast<const bf16x8*>(wrow + k0);
#pragma unroll
            for (int j = 0; j < 8; ++j) acc += e_s[k0 + j] * (float)wv[j];
        }
    } else {
        const float* wrow = (const float*)w_ih_raw + tid * EMB;
#pragma unroll
        for (int k0 = 0; k0 < EMB; k0 += 4) {
            floatx4 wv = *reinterpret_cast<const floatx4*>(wrow + k0);
#pragma unroll
            for (int j = 0; j < 4; ++j) acc += e_s[k0 + j] * wv[j];
        }
    }
    xp[m * G3 + tid] = acc;
}

// ---------------------------------------------------------------------------
// K2: sequential GRU scan — ONE WAVE PER BATCH, zero barriers, zero LDS.
// Thread j owns hidden unit j; w_hh rows r/z/n live in 96 float2 VGPR pairs.
// h broadcast via v_readlane, BATCHED in groups of 16 so the independent
// readlanes pipeline into SGPRs instead of serializing readlane->use stalls.
// Dot products written as float2 so the compiler can emit v_pk_fma_f32.
// ---------------------------------------------------------------------------
__global__ __launch_bounds__(64, 1) void k_gru_scan(
    const float* __restrict__ xp,
    const void* __restrict__ w_hh_raw,
    const void* __restrict__ b_hh_raw,
    __hip_bfloat16* __restrict__ hs)
{
    const bool isbf = detect_bf16(w_hh_raw);
    const int b = blockIdx.x;
    const int j = threadIdx.x;   // 0..63, owns hidden unit j

    floatx2 wr2[HID / 2], wz2[HID / 2], wn2[HID / 2];
    if (isbf) {
        const __hip_bfloat16* w = (const __hip_bfloat16*)w_hh_raw;
#pragma unroll
        for (int k0 = 0; k0 < HID; k0 += 8) {
            bf16x8 v0 = *reinterpret_cast<const bf16x8*>(w + (          j) * HID + k0);
            bf16x8 v1 = *reinterpret_cast<const bf16x8*>(w + (HID     + j) * HID + k0);
            bf16x8 v2 = *reinterpret_cast<const bf16x8*>(w + (2 * HID + j) * HID + k0);
#pragma unroll
            for (int t = 0; t < 4; ++t) {
                wr2[(k0 >> 1) + t] = (floatx2){(float)v0[2 * t], (float)v0[2 * t + 1]};
                wz2[(k0 >> 1) + t] = (floatx2){(float)v1[2 * t], (float)v1[2 * t + 1]};
                wn2[(k0 >> 1) + t] = (floatx2){(float)v2[2 * t], (float)v2[2 * t + 1]};
            }
        }
    } else {
        const float* w = (const float*)w_hh_raw;
#pragma unroll
        for (int k0 = 0; k0 < HID; k0 += 4) {
            floatx4 v0 = *reinterpret_cast<const floatx4*>(w + (          j) * HID + k0);
            floatx4 v1 = *reinterpret_cast<const floatx4*>(w + (HID     + j) * HID + k0);
            floatx4 v2 = *reinterpret_cast<const floatx4*>(w + (2 * HID + j) * HID + k0);
#pragma unroll
            for (int t = 0; t < 2; ++t) {
                wr2[(k0 >> 1) + t] = (floatx2){v0[2 * t], v0[2 * t + 1]};
                wz2[(k0 >> 1) + t] = (floatx2){v1[2 * t], v1[2 * t + 1]};
                wn2[(k0 >> 1) + t] = (floatx2){v2[2 * t], v2[2 * t + 1]};
            }
        }
    }

    float bhr, bhz, bhn;
    if (isbf) {
        const __hip_bfloat16* bb = (const __hip_bfloat16*)b_hh_raw;
        bhr = bf2f(bb[j]); bhz = bf2f(bb[HID + j]); bhn = bf2f(bb[2 * HID + j]);
    } else {
        const float* bb = (const float*)b_hh_raw;
        bhr = bb[j]; bhz = bb[HID + j]; bhn = bb[2 * HID + j];
    }

    const float* xpb = xp + (size_t)b * NS * G3;
    float xr = xpb[j], xz = xpb[HID + j], xn = xpb[2 * HID + j];
    float h = 0.f;

    for (int s = 0; s < NS; ++s) {
        // prefetch next step's x-projections (independent of h; hides HBM latency)
        float nxr = 0.f, nxz = 0.f, nxn = 0.f;
        if (s + 1 < NS) {
            const float* xrow = xpb + (s + 1) * G3;
            nxr = xrow[j]; nxz = xrow[HID + j]; nxn = xrow[2 * HID + j];
        }

        floatx2 ar0 = {0.f, 0.f}, ar1 = {0.f, 0.f};
        floatx2 az0 = {0.f, 0.f}, az1 = {0.f, 0.f};
        floatx2 an0 = {0.f, 0.f}, an1 = {0.f, 0.f};
#pragma unroll
        for (int kk = 0; kk < HID; kk += 16) {
            // batch 16 independent broadcasts -> SGPRs (pipelined, no per-use stall)
            float hb[16];
#pragma unroll
            for (int t = 0; t < 16; ++t) hb[t] = bcastf(h, kk + t);
#pragma unroll
            for (int p = 0; p < 8; ++p) {
                const int w = (kk >> 1) + p;
                floatx2 hv;
                hv[0] = hb[2 * p];
                hv[1] = hb[2 * p + 1];
                if (p & 1) { ar1 += hv * wr2[w]; az1 += hv * wz2[w]; an1 += hv * wn2[w]; }
                else       { ar0 += hv * wr2[w]; az0 += hv * wz2[w]; an0 += hv * wn2[w]; }
            }
        }
        const float arf = (ar0[0] + ar0[1]) + (ar1[0] + ar1[1]);
        const float azf = (az0[0] + az0[1]) + (az1[0] + az1[1]);
        const float anf = (an0[0] + an0[1]) + (an1[0] + an1[1]);

        const float r = __fdividef(1.f, 1.f + __expf(-(xr + arf + bhr)));
        const float z = __fdividef(1.f, 1.f + __expf(-(xz + azf + bhz)));
        const float n = __fdividef(2.f, 1.f + __expf(-2.f * (xn + r * (anf + bhn)))) - 1.f;
        h = (1.f - z) * n + z * h;

        hs[((size_t)b * NS + s) * HID + j] = __float2bfloat16(h);
        xr = nxr; xz = nxz; xn = nxn;
    }
}

// ---------------------------------------------------------------------------
// K3: out[m][v] = sum_k hs[m][k] * w_out[v][k] + b_out[v].
// mfma_f32_16x16x32_bf16; block = 4 waves, each wave does 16(M)x64(N).
// Grid: x = mtile (fast-varying), y = ncb. Consecutive blocks share the same
// w_out slice (same ncb) -> each XCD's L2 fetches each 65KB slice once
// instead of re-fetching it for every mtile (was 1.02 GB of FETCH).
// Stores staged through LDS -> full-line-covered 256B row writes.
// ---------------------------------------------------------------------------
__global__ __launch_bounds__(256) void k_logits(
    const __hip_bfloat16* __restrict__ hs,
    const void* __restrict__ w_out_raw,
    const void* __restrict__ b_out_raw,
    void* __restrict__ out_raw)
{
    const bool isbf = detect_bf16(w_out_raw);
    const int mtile = blockIdx.x;            // 0..255 (16 rows each)  [fast dim]
    const int ncb   = blockIdx.y;            // 0..124 (256 cols each)
    const int wave  = threadIdx.x >> 6;      // 0..3
    const int lane  = threadIdx.x & 63;
    const int quad  = lane >> 4;
    const int l15   = lane & 15;

    // stride 68: keeps 16B alignment for float4 reads, staggers banks by 4/row
    __shared__ float tile[4][16][68];

    const __hip_bfloat16* arow = hs + (mtile * 16 + l15) * HID;
    const bf16x8 a0 = *reinterpret_cast<const bf16x8*>(arow + quad * 8);
    const bf16x8 a1 = *reinterpret_cast<const bf16x8*>(arow + 32 + quad * 8);

    const int ncol_wave = ncb * 256 + wave * 64;
#pragma unroll
    for (int t = 0; t < 4; ++t) {
        const int ncol = ncol_wave + t * 16;
        bf16x8 b0, b1;
        if (isbf) {
            const __hip_bfloat16* brow = (const __hip_bfloat16*)w_out_raw + (ncol + l15) * HID;
            b0 = *reinterpret_cast<const bf16x8*>(brow + quad * 8);
            b1 = *reinterpret_cast<const bf16x8*>(brow + 32 + quad * 8);
        } else {
            const float* browf = (const float*)w_out_raw + (ncol + l15) * HID;
            floatx4 f0 = *reinterpret_cast<const floatx4*>(browf + quad * 8);
            floatx4 f1 = *reinterpret_cast<const floatx4*>(browf + quad * 8 + 4);
            floatx4 f2 = *reinterpret_cast<const floatx4*>(browf + 32 + quad * 8);
            floatx4 f3 = *reinterpret_cast<const floatx4*>(browf + 32 + quad * 8 + 4);
            short8 s0, s1;
#pragma unroll
            for (int j = 0; j < 4; ++j) {
                s0[j] = f2bf_bits(f0[j]); s0[4 + j] = f2bf_bits(f1[j]);
                s1[j] = f2bf_bits(f2[j]); s1[4 + j] = f2bf_bits(f3[j]);
            }
            b0 = __builtin_bit_cast(bf16x8, s0);
            b1 = __builtin_bit_cast(bf16x8, s1);
        }

        floatx4 acc = {0.f, 0.f, 0.f, 0.f};
        acc = __builtin_amdgcn_mfma_f32_16x16x32_bf16(a0, b0, acc, 0, 0, 0);
        acc = __builtin_amdgcn_mfma_f32_16x16x32_bf16(a1, b1, acc, 0, 0, 0);

        const float bias = isbf ? bf2f(((const __hip_bfloat16*)b_out_raw)[ncol + l15])
                                : ((const float*)b_out_raw)[ncol + l15];
        // C layout: col = lane&15, row = quad*4 + i  →  stage into LDS
#pragma unroll
        for (int i = 0; i < 4; ++i)
            tile[wave][quad * 4 + i][t * 16 + l15] = acc[i] + bias;
    }
    __syncthreads();   // LDS visibility (intra-wave dep; barrier is one-shot & cheap)

    // Coalesced writeback: per p, quad q writes row p*4+q, lanes cover 64
    // consecutive floats as float4 → 256 B contiguous, full cache lines.
    if (isbf) {
        short* outb = (short*)out_raw;
#pragma unroll
        for (int p = 0; p < 4; ++p) {
            const int row = p * 4 + quad;
            const float* src = &tile[wave][row][l15 * 4];
            short4v u;
#pragma unroll
            for (int jj = 0; jj < 4; ++jj) u[jj] = f2bf_bits(src[jj]);
            *reinterpret_cast<short4v*>(
                outb + (size_t)(mtile * 16 + row) * VOCAB + ncol_wave + l15 * 4) = u;
        }
    } else {
        float* outf = (float*)out_raw;
#pragma unroll
        for (int p = 0; p < 4; ++p) {
            const int row = p * 4 + quad;
            floatx4 v = *reinterpret_cast<const floatx4*>(&tile[wave][row][l15 * 4]);
            *reinterpret_cast<floatx4*>(
                outf + (size_t)(mtile * 16 + row) * VOCAB + ncol_wave + l15 * 4) = v;
        }
    }
}

// ---------------------------------------------------------------------------
extern "C" void kernel_launch(void* const* d_in, const int* in_sizes, int n_in,
                              void* d_out, int out_size, void* d_ws, size_t ws_size,
                              hipStream_t stream)
{
    const int*  tokens = (const int*)d_in[0];
    const void* emb    = d_in[1];
    const void* w_ih   = d_in[2];
    const void* w_hh   = d_in[3];
    const void* b_ih   = d_in[4];
    const void* b_hh   = d_in[5];
    const void* w_out  = d_in[6];
    const void* b_out  = d_in[7];

    // xp scratch lives in d_out's first 3 MiB (dead until k_logits overwrites
    // the whole output); hs (512 KiB) is the only d_ws use.
    float* xp = (float*)d_out;
    __hip_bfloat16* hs = (__hip_bfloat16*)d_ws;

    k_embed_proj<<<NB * NS, G3, 0, stream>>>(tokens, emb, w_ih, b_ih, xp);
    k_gru_scan<<<NB, 64, 0, stream>>>(xp, w_hh, b_hh, hs);
    dim3 grid3((NB * NS) / 16, VOCAB / 256);   // x = mtile (fast), y = ncb
    k_logits<<<grid3, 256, 0, stream>>>(hs, w_out, b_out, d_out);
}